// Round 1
// baseline (456.715 us; speedup 1.0000x reference)
//
#include <hip/hip_runtime.h>
#include <cstdint>

#define GNY 1024
#define GNX 2048
#define GNPTS (GNY * GNX)

namespace {
constexpr float DT = 0.1f;
constexpr float NUc = 0.01f;
constexpr float INV_DIAG = -0.375f;   // 1/DIAG, DIAG = -8/(3*dx^2) = -8/3
constexpr int NLEVEL = 11;
}

// ---- boundary-condition index maps (verified against JAX .at[].set order) ----
__device__ __forceinline__ float bc_u_at(const float* __restrict__ f, int y, int x) {
    // top/bottom ghost rows = UB everywhere; left ghost col = UB; right ghost = copy last col
    if (y < 0 || y >= GNY || x < 0) return 1.0f;
    if (x >= GNX) x = GNX - 1;
    return f[y * GNX + x];
}
__device__ __forceinline__ float bc_v_at(const float* __restrict__ f, int y, int x) {
    // zero ghost except right ghost col (interior rows) = copy last col
    if (y < 0 || y >= GNY || x < 0) return 0.0f;
    if (x >= GNX) x = GNX - 1;
    return f[y * GNX + x];
}
__device__ __forceinline__ float bc_p_at(const float* __restrict__ f, int y, int x) {
    // right ghost = 0 (dominates corners); left/top/bottom mirror (clamp)
    if (x >= GNX) return 0.0f;
    if (x < 0) x = 0;
    y = min(max(y, 0), GNY - 1);
    return f[y * GNX + x];
}

// ---- stencils (cross-correlation, m[dy][dx] = f(y+dy-1, x+dx-1)) ----
__device__ __forceinline__ float conv_x3(const float m[3][3]) {
    return ((m[0][2] - m[0][0]) + 4.0f * (m[1][2] - m[1][0]) + (m[2][2] - m[2][0])) * (1.0f / 12.0f);
}
__device__ __forceinline__ float conv_y3(const float m[3][3]) {
    return ((m[2][0] - m[0][0]) + 4.0f * (m[2][1] - m[0][1]) + (m[2][2] - m[0][2])) * (1.0f / 12.0f);
}
__device__ __forceinline__ float conv_d3(const float m[3][3]) {
    return (m[0][0] + m[0][1] + m[0][2] + m[1][0] + m[1][2] + m[2][0] + m[2][1] + m[2][2]
            - 8.0f * m[1][1]) * (1.0f / 3.0f);
}

// ---- momentum predictor: bu,bv (damped) ----
__global__ __launch_bounds__(256) void k_predict(
        const float* __restrict__ u, const float* __restrict__ v,
        const float* __restrict__ p, const float* __restrict__ sigma,
        float* __restrict__ bu, float* __restrict__ bv) {
    int x = blockIdx.x * blockDim.x + threadIdx.x;
    int y = blockIdx.y * blockDim.y + threadIdx.y;
    if (x >= GNX || y >= GNY) return;
    float un[3][3], vn[3][3], pn[3][3];
#pragma unroll
    for (int dy = 0; dy < 3; ++dy)
#pragma unroll
        for (int dx = 0; dx < 3; ++dx) {
            int yy = y + dy - 1, xx = x + dx - 1;
            un[dy][dx] = bc_u_at(u, yy, xx);
            vn[dy][dx] = bc_v_at(v, yy, xx);
            pn[dy][dx] = bc_p_at(p, yy, xx);
        }
    float gx = conv_x3(pn) * DT, gy = conv_y3(pn) * DT;
    float uc = un[1][1], vc = vn[1][1];
    float damp = 1.0f / (1.0f + DT * sigma[y * GNX + x]);
    float bu_ = uc + 0.5f * (NUc * conv_d3(un) * DT - uc * conv_x3(un) * DT - vc * conv_y3(un) * DT) - gx;
    float bv_ = vc + 0.5f * (NUc * conv_d3(vn) * DT - uc * conv_x3(vn) * DT - vc * conv_y3(vn) * DT) - gy;
    bu[y * GNX + x] = bu_ * damp;
    bv[y * GNX + x] = bv_ * damp;
}

// ---- momentum corrector: u2,v2 (damped); recomputes Grapx/Grapy from pristine p ----
__global__ __launch_bounds__(256) void k_correct(
        const float* __restrict__ u, const float* __restrict__ v,
        const float* __restrict__ p, const float* __restrict__ sigma,
        const float* __restrict__ bu, const float* __restrict__ bv,
        float* __restrict__ u2, float* __restrict__ v2) {
    int x = blockIdx.x * blockDim.x + threadIdx.x;
    int y = blockIdx.y * blockDim.y + threadIdx.y;
    if (x >= GNX || y >= GNY) return;
    float bun[3][3], bvn[3][3], pn[3][3];
#pragma unroll
    for (int dy = 0; dy < 3; ++dy)
#pragma unroll
        for (int dx = 0; dx < 3; ++dx) {
            int yy = y + dy - 1, xx = x + dx - 1;
            bun[dy][dx] = bc_u_at(bu, yy, xx);
            bvn[dy][dx] = bc_v_at(bv, yy, xx);
            pn[dy][dx] = bc_p_at(p, yy, xx);
        }
    float gx = conv_x3(pn) * DT, gy = conv_y3(pn) * DT;
    float buc = bun[1][1], bvc = bvn[1][1];
    int idx = y * GNX + x;
    float damp = 1.0f / (1.0f + DT * sigma[idx]);
    float un_ = u[idx] + NUc * conv_d3(bun) * DT - buc * conv_x3(bun) * DT - bvc * conv_y3(bun) * DT - gx;
    float vn_ = v[idx] + NUc * conv_d3(bvn) * DT - buc * conv_x3(bvn) * DT - bvc * conv_y3(bvn) * DT - gy;
    u2[idx] = un_ * damp;
    v2[idx] = vn_ * damp;
}

// ---- MG rhs: b = -(d/dx u + d/dy v)/DT ----
__global__ __launch_bounds__(256) void k_rhs(
        const float* __restrict__ u2, const float* __restrict__ v2, float* __restrict__ b) {
    int x = blockIdx.x * blockDim.x + threadIdx.x;
    int y = blockIdx.y * blockDim.y + threadIdx.y;
    if (x >= GNX || y >= GNY) return;
    float un[3][3], vn[3][3];
#pragma unroll
    for (int dy = 0; dy < 3; ++dy)
#pragma unroll
        for (int dx = 0; dx < 3; ++dx) {
            int yy = y + dy - 1, xx = x + dx - 1;
            un[dy][dx] = bc_u_at(u2, yy, xx);
            vn[dy][dx] = bc_v_at(v2, yy, xx);
        }
    b[y * GNX + x] = -(conv_x3(un) + conv_y3(vn)) * (1.0f / DT);
}

// ---- residual r = A p - b at full res ----
__global__ __launch_bounds__(256) void k_resid(
        const float* __restrict__ p, const float* __restrict__ b, float* __restrict__ r) {
    int x = blockIdx.x * blockDim.x + threadIdx.x;
    int y = blockIdx.y * blockDim.y + threadIdx.y;
    if (x >= GNX || y >= GNY) return;
    float pn[3][3];
#pragma unroll
    for (int dy = 0; dy < 3; ++dy)
#pragma unroll
        for (int dx = 0; dx < 3; ++dx)
            pn[dy][dx] = bc_p_at(p, y + dy - 1, x + dx - 1);
    int idx = y * GNX + x;
    r[idx] = conv_d3(pn) - b[idx];
}

// ---- 2x2 average restriction ----
__global__ void k_restrict(const float* __restrict__ fin, float* __restrict__ fout,
                           int Hout, int Wout) {
    int i = blockIdx.x * blockDim.x + threadIdx.x;
    if (i >= Hout * Wout) return;
    int y = i / Wout, x = i - y * Wout;
    int Win = Wout * 2;
    const float* r0 = fin + (2 * y) * Win + 2 * x;
    fout[i] = 0.25f * (r0[0] + r0[1] + r0[Win] + r0[Win + 1]);
}

// ---- coarse-to-fine: a = P(a_in) - A(bc0(P(a_in)))/DIAG + r/DIAG ----
// prolongation folded into the gather; ascale=1/DIAG folds the coarsest a=r/DIAG step
__global__ void k_up(const float* __restrict__ a_in, float ascale,
                     const float* __restrict__ r, float* __restrict__ a_out,
                     int H, int W) {
    int i = blockIdx.x * blockDim.x + threadIdx.x;
    if (i >= H * W) return;
    int y = i / W, x = i - y * W;
    int Wc = W >> 1;
    float m[3][3];
#pragma unroll
    for (int dy = 0; dy < 3; ++dy)
#pragma unroll
        for (int dx = 0; dx < 3; ++dx) {
            int yy = y + dy - 1, xx = x + dx - 1;
            m[dy][dx] = (yy >= 0 && yy < H && xx >= 0 && xx < W)
                            ? a_in[(yy >> 1) * Wc + (xx >> 1)] * ascale
                            : 0.0f;
        }
    float conv = (m[0][0] + m[0][1] + m[0][2] + m[1][0] + m[1][2] + m[2][0] + m[2][1] + m[2][2]
                  - 8.0f * m[1][1]) * (1.0f / 3.0f);
    a_out[i] = m[1][1] - conv * INV_DIAG + r[i] * INV_DIAG;
}

// ---- fused: p' = p - P(a1);  p_new = p' - A(bc_p(p'))/DIAG + b/DIAG ----
__global__ __launch_bounds__(256) void k_pupdate(
        const float* __restrict__ p_src, const float* __restrict__ a1,
        const float* __restrict__ b, float* __restrict__ p_dst) {
    int x = blockIdx.x * blockDim.x + threadIdx.x;
    int y = blockIdx.y * blockDim.y + threadIdx.y;
    if (x >= GNX || y >= GNY) return;
    float m[3][3];
#pragma unroll
    for (int dy = 0; dy < 3; ++dy)
#pragma unroll
        for (int dx = 0; dx < 3; ++dx) {
            int yy = y + dy - 1, xx = x + dx - 1;
            float val;
            if (xx >= GNX) {
                val = 0.0f;  // bc_p right ghost (dominates corners)
            } else {
                if (xx < 0) xx = 0;
                yy = min(max(yy, 0), GNY - 1);
                val = p_src[yy * GNX + xx] - a1[(yy >> 1) * (GNX >> 1) + (xx >> 1)];
            }
            m[dy][dx] = val;
        }
    float conv = (m[0][0] + m[0][1] + m[0][2] + m[1][0] + m[1][2] + m[2][0] + m[2][1] + m[2][2]
                  - 8.0f * m[1][1]) * (1.0f / 3.0f);
    int idx = y * GNX + x;
    p_dst[idx] = m[1][1] - conv * INV_DIAG + b[idx] * INV_DIAG;
}

// ---- final projection: u -= dp/dx*DT etc., damped (in-place on u2/v2) ----
__global__ __launch_bounds__(256) void k_project(
        const float* __restrict__ p, const float* __restrict__ sigma,
        float* __restrict__ u_io, float* __restrict__ v_io) {
    int x = blockIdx.x * blockDim.x + threadIdx.x;
    int y = blockIdx.y * blockDim.y + threadIdx.y;
    if (x >= GNX || y >= GNY) return;
    float pn[3][3];
#pragma unroll
    for (int dy = 0; dy < 3; ++dy)
#pragma unroll
        for (int dx = 0; dx < 3; ++dx)
            pn[dy][dx] = bc_p_at(p, y + dy - 1, x + dx - 1);
    int idx = y * GNX + x;
    float damp = 1.0f / (1.0f + DT * sigma[idx]);
    u_io[idx] = (u_io[idx] - conv_x3(pn) * DT) * damp;
    v_io[idx] = (v_io[idx] - conv_y3(pn) * DT) * damp;
}

extern "C" void kernel_launch(void* const* d_in, const int* in_sizes, int n_in,
                              void* d_out, int out_size, void* d_ws, size_t ws_size,
                              hipStream_t stream) {
    (void)in_sizes; (void)n_in; (void)out_size; (void)ws_size;
    const float* u_in  = (const float*)d_in[0];
    const float* v_in  = (const float*)d_in[1];
    const float* p_in  = (const float*)d_in[2];
    const float* sigma = (const float*)d_in[3];
    // d_in[4..8] are the fixed stencil weights — hardcoded above.

    float* out_u = (float*)d_out;
    float* out_v = out_u + GNPTS;
    float* out_p = out_u + 2 * (size_t)GNPTS;

    float* ws   = (float*)d_ws;
    float* bu   = ws;
    float* bv   = ws + (size_t)GNPTS;
    float* b    = ws + 2 * (size_t)GNPTS;
    float* p_ws = ws + 3 * (size_t)GNPTS;
    float* rpyr = ws + 4 * (size_t)GNPTS;

    int Hs[NLEVEL], Wl[NLEVEL];
    size_t roff[NLEVEL];
    size_t acc = 0;
    for (int l = 0; l < NLEVEL; ++l) {
        Hs[l] = GNY >> l; Wl[l] = GNX >> l;
        roff[l] = acc; acc += (size_t)Hs[l] * Wl[l];
    }
    float* a_ping = rpyr + acc;
    float* a_pong = a_ping + (GNPTS / 4);

    dim3 blk2(64, 4), grd2(GNX / 64, GNY / 4);

    k_predict<<<grd2, blk2, 0, stream>>>(u_in, v_in, p_in, sigma, bu, bv);
    k_correct<<<grd2, blk2, 0, stream>>>(u_in, v_in, p_in, sigma, bu, bv, out_u, out_v);
    k_rhs<<<grd2, blk2, 0, stream>>>(out_u, out_v, b);

    const float* p_cur = p_in;          // pristine input p; read-only
    float* p_bufs[2] = { out_p, p_ws }; // it0->out_p, it1->p_ws, ..., it4->out_p
    for (int it = 0; it < 5; ++it) {
        k_resid<<<grd2, blk2, 0, stream>>>(p_cur, b, rpyr);
        for (int l = 1; l < NLEVEL; ++l) {
            int n = Hs[l] * Wl[l];
            int g = (n + 255) / 256;
            k_restrict<<<dim3(g), dim3(256), 0, stream>>>(rpyr + roff[l - 1], rpyr + roff[l],
                                                          Hs[l], Wl[l]);
        }
        const float* ain = rpyr + roff[10];
        float ascale = INV_DIAG;        // folds a10 = r10/DIAG
        float* aout = a_ping;
        for (int i = 9; i >= 1; --i) {
            int n = Hs[i] * Wl[i];
            int g = (n + 255) / 256;
            k_up<<<dim3(g), dim3(256), 0, stream>>>(ain, ascale, rpyr + roff[i], aout,
                                                    Hs[i], Wl[i]);
            ain = aout; ascale = 1.0f;
            aout = (aout == a_ping) ? a_pong : a_ping;
        }
        float* p_next = p_bufs[it % 2];
        k_pupdate<<<grd2, blk2, 0, stream>>>(p_cur, ain, b, p_next);
        p_cur = p_next;
    }
    // p_cur == out_p here
    k_project<<<grd2, blk2, 0, stream>>>(p_cur, sigma, out_u, out_v);
}

// Round 2
// 373.265 us; speedup vs baseline: 1.2236x; 1.2236x over previous
//
#include <hip/hip_runtime.h>
#include <cstdint>

#define GNY 1024
#define GNX 2048
#define GNPTS (GNY * GNX)

namespace {
constexpr float DT = 0.1f;
constexpr float NUc = 0.01f;
constexpr float INV_DIAG = -0.375f;   // 1/DIAG, DIAG = -8/(3*dx^2) = -8/3
}

// ---- boundary-condition index maps (verified against JAX .at[].set order) ----
__device__ __forceinline__ float bc_u_at(const float* __restrict__ f, int y, int x) {
    if (y < 0 || y >= GNY || x < 0) return 1.0f;
    if (x >= GNX) x = GNX - 1;
    return f[y * GNX + x];
}
__device__ __forceinline__ float bc_v_at(const float* __restrict__ f, int y, int x) {
    if (y < 0 || y >= GNY || x < 0) return 0.0f;
    if (x >= GNX) x = GNX - 1;
    return f[y * GNX + x];
}
__device__ __forceinline__ float bc_p_at(const float* __restrict__ f, int y, int x) {
    if (x >= GNX) return 0.0f;          // right ghost = 0 (dominates corners)
    if (x < 0) x = 0;
    y = min(max(y, 0), GNY - 1);
    return f[y * GNX + x];
}

// ---- stencils (cross-correlation, m[dy][dx] = f(y+dy-1, x+dx-1)) ----
__device__ __forceinline__ float conv_x3(const float m[3][3]) {
    return ((m[0][2] - m[0][0]) + 4.0f * (m[1][2] - m[1][0]) + (m[2][2] - m[2][0])) * (1.0f / 12.0f);
}
__device__ __forceinline__ float conv_y3(const float m[3][3]) {
    return ((m[2][0] - m[0][0]) + 4.0f * (m[2][1] - m[0][1]) + (m[2][2] - m[0][2])) * (1.0f / 12.0f);
}
__device__ __forceinline__ float conv_d3(const float m[3][3]) {
    return (m[0][0] + m[0][1] + m[0][2] + m[1][0] + m[1][2] + m[2][0] + m[2][1] + m[2][2]
            - 8.0f * m[1][1]) * (1.0f / 3.0f);
}

// ---- momentum predictor: bu,bv (damped) ----
__global__ __launch_bounds__(256) void k_predict(
        const float* __restrict__ u, const float* __restrict__ v,
        const float* __restrict__ p, const float* __restrict__ sigma,
        float* __restrict__ bu, float* __restrict__ bv) {
    int x = blockIdx.x * blockDim.x + threadIdx.x;
    int y = blockIdx.y * blockDim.y + threadIdx.y;
    if (x >= GNX || y >= GNY) return;
    float un[3][3], vn[3][3], pn[3][3];
#pragma unroll
    for (int dy = 0; dy < 3; ++dy)
#pragma unroll
        for (int dx = 0; dx < 3; ++dx) {
            int yy = y + dy - 1, xx = x + dx - 1;
            un[dy][dx] = bc_u_at(u, yy, xx);
            vn[dy][dx] = bc_v_at(v, yy, xx);
            pn[dy][dx] = bc_p_at(p, yy, xx);
        }
    float gx = conv_x3(pn) * DT, gy = conv_y3(pn) * DT;
    float uc = un[1][1], vc = vn[1][1];
    float damp = 1.0f / (1.0f + DT * sigma[y * GNX + x]);
    float bu_ = uc + 0.5f * (NUc * conv_d3(un) * DT - uc * conv_x3(un) * DT - vc * conv_y3(un) * DT) - gx;
    float bv_ = vc + 0.5f * (NUc * conv_d3(vn) * DT - uc * conv_x3(vn) * DT - vc * conv_y3(vn) * DT) - gy;
    bu[y * GNX + x] = bu_ * damp;
    bv[y * GNX + x] = bv_ * damp;
}

// ---- momentum corrector (recomputes Grapx/Grapy from pristine p) ----
__global__ __launch_bounds__(256) void k_correct(
        const float* __restrict__ u, const float* __restrict__ v,
        const float* __restrict__ p, const float* __restrict__ sigma,
        const float* __restrict__ bu, const float* __restrict__ bv,
        float* __restrict__ u2, float* __restrict__ v2) {
    int x = blockIdx.x * blockDim.x + threadIdx.x;
    int y = blockIdx.y * blockDim.y + threadIdx.y;
    if (x >= GNX || y >= GNY) return;
    float bun[3][3], bvn[3][3], pn[3][3];
#pragma unroll
    for (int dy = 0; dy < 3; ++dy)
#pragma unroll
        for (int dx = 0; dx < 3; ++dx) {
            int yy = y + dy - 1, xx = x + dx - 1;
            bun[dy][dx] = bc_u_at(bu, yy, xx);
            bvn[dy][dx] = bc_v_at(bv, yy, xx);
            pn[dy][dx] = bc_p_at(p, yy, xx);
        }
    float gx = conv_x3(pn) * DT, gy = conv_y3(pn) * DT;
    float buc = bun[1][1], bvc = bvn[1][1];
    int idx = y * GNX + x;
    float damp = 1.0f / (1.0f + DT * sigma[idx]);
    float un_ = u[idx] + NUc * conv_d3(bun) * DT - buc * conv_x3(bun) * DT - bvc * conv_y3(bun) * DT - gx;
    float vn_ = v[idx] + NUc * conv_d3(bvn) * DT - buc * conv_x3(bvn) * DT - bvc * conv_y3(bvn) * DT - gy;
    u2[idx] = un_ * damp;
    v2[idx] = vn_ * damp;
}

// ---- MG rhs: b = -(d/dx u + d/dy v)/DT ----
__global__ __launch_bounds__(256) void k_rhs(
        const float* __restrict__ u2, const float* __restrict__ v2, float* __restrict__ b) {
    int x = blockIdx.x * blockDim.x + threadIdx.x;
    int y = blockIdx.y * blockDim.y + threadIdx.y;
    if (x >= GNX || y >= GNY) return;
    float un[3][3], vn[3][3];
#pragma unroll
    for (int dy = 0; dy < 3; ++dy)
#pragma unroll
        for (int dx = 0; dx < 3; ++dx) {
            int yy = y + dy - 1, xx = x + dx - 1;
            un[dy][dx] = bc_u_at(u2, yy, xx);
            vn[dy][dx] = bc_v_at(v2, yy, xx);
        }
    b[y * GNX + x] = -(conv_x3(un) + conv_y3(vn)) * (1.0f / DT);
}

// ---- fused residual + restriction to levels 1..5 (32x32 tile per WG) ----
// r0 = A p - b is computed in LDS and never written to global (it is unused).
__global__ __launch_bounds__(256) void k_resid_restrict(
        const float* __restrict__ p, const float* __restrict__ b,
        float* __restrict__ r1, float* __restrict__ r2, float* __restrict__ r3,
        float* __restrict__ r4, float* __restrict__ r5) {
    __shared__ float s0[32][33];
    __shared__ float s1[16][17];
    __shared__ float s2[8][9];
    __shared__ float s3[4][5];
    __shared__ float s4[2][3];
    int t = threadIdx.x;
    int tx = t & 31, tg = t >> 5;             // 8 row-groups x 4 rows
    int x0 = blockIdx.x * 32, y0 = blockIdx.y * 32;
    int x = x0 + tx;
#pragma unroll
    for (int ry = 0; ry < 4; ++ry) {
        int yr = tg * 4 + ry;
        int y = y0 + yr;
        float pn[3][3];
#pragma unroll
        for (int dy = 0; dy < 3; ++dy)
#pragma unroll
            for (int dx = 0; dx < 3; ++dx)
                pn[dy][dx] = bc_p_at(p, y + dy - 1, x + dx - 1);
        s0[yr][tx] = conv_d3(pn) - b[y * GNX + x];
    }
    __syncthreads();
    {   // level 1: 16x16, W=1024
        int qy = t >> 4, qx = t & 15;
        float v = 0.25f * (s0[2*qy][2*qx] + s0[2*qy][2*qx+1] + s0[2*qy+1][2*qx] + s0[2*qy+1][2*qx+1]);
        s1[qy][qx] = v;
        r1[(blockIdx.y * 16 + qy) * 1024 + blockIdx.x * 16 + qx] = v;
    }
    __syncthreads();
    if (t < 64) {   // level 2: 8x8, W=512
        int qy = t >> 3, qx = t & 7;
        float v = 0.25f * (s1[2*qy][2*qx] + s1[2*qy][2*qx+1] + s1[2*qy+1][2*qx] + s1[2*qy+1][2*qx+1]);
        s2[qy][qx] = v;
        r2[(blockIdx.y * 8 + qy) * 512 + blockIdx.x * 8 + qx] = v;
    }
    __syncthreads();
    if (t < 16) {   // level 3: 4x4, W=256
        int qy = t >> 2, qx = t & 3;
        float v = 0.25f * (s2[2*qy][2*qx] + s2[2*qy][2*qx+1] + s2[2*qy+1][2*qx] + s2[2*qy+1][2*qx+1]);
        s3[qy][qx] = v;
        r3[(blockIdx.y * 4 + qy) * 256 + blockIdx.x * 4 + qx] = v;
    }
    __syncthreads();
    if (t < 4) {    // level 4: 2x2, W=128
        int qy = t >> 1, qx = t & 1;
        float v = 0.25f * (s3[2*qy][2*qx] + s3[2*qy][2*qx+1] + s3[2*qy+1][2*qx] + s3[2*qy+1][2*qx+1]);
        s4[qy][qx] = v;
        r4[(blockIdx.y * 2 + qy) * 128 + blockIdx.x * 2 + qx] = v;
    }
    __syncthreads();
    if (t == 0) {   // level 5: 1x1, W=64
        r5[blockIdx.y * 64 + blockIdx.x] = 0.25f * (s4[0][0] + s4[0][1] + s4[1][0] + s4[1][1]);
    }
}

// ---- one up-sweep smoothing step, homogeneous halo, any memory space ----
__device__ __forceinline__ void up_step(float* __restrict__ out,
        const float* __restrict__ ain, const float* __restrict__ r,
        int H, int W, int t) {
    int Wc = W >> 1;
    for (int i = t; i < H * W; i += 256) {
        int y = i / W, x = i - y * W;
        float m[3][3];
#pragma unroll
        for (int dy = 0; dy < 3; ++dy)
#pragma unroll
            for (int dx = 0; dx < 3; ++dx) {
                int yy = y + dy - 1, xx = x + dx - 1;
                m[dy][dx] = (yy >= 0 && yy < H && xx >= 0 && xx < W)
                                ? ain[(yy >> 1) * Wc + (xx >> 1)] : 0.0f;
            }
        float conv = (m[0][0] + m[0][1] + m[0][2] + m[1][0] + m[1][2]
                      + m[2][0] + m[2][1] + m[2][2] - 8.0f * m[1][1]) * (1.0f / 3.0f);
        out[i] = m[1][1] - conv * INV_DIAG + r[i] * INV_DIAG;
    }
}

// ---- single-WG coarse solve: restrict r5->r10, up-sweep a10->a4, all in LDS ----
__global__ __launch_bounds__(256) void k_coarse(
        const float* __restrict__ r5g, const float* __restrict__ r4g,
        float* __restrict__ a4g) {
    __shared__ float s5[2048], s6[512], s7[128], s8[32], s9[8], s10[2];
    __shared__ float aA[512], aB[2048];
    int t = threadIdx.x;
    for (int i = t; i < 2048; i += 256) s5[i] = r5g[i];
    __syncthreads();
    for (int i = t; i < 512; i += 256) {        // r6: 16x32
        int y = i >> 5, x = i & 31;
        s6[i] = 0.25f * (s5[(2*y)*64 + 2*x] + s5[(2*y)*64 + 2*x + 1]
                       + s5[(2*y+1)*64 + 2*x] + s5[(2*y+1)*64 + 2*x + 1]);
    }
    __syncthreads();
    if (t < 128) {                              // r7: 8x16
        int y = t >> 4, x = t & 15;
        s7[t] = 0.25f * (s6[(2*y)*32 + 2*x] + s6[(2*y)*32 + 2*x + 1]
                       + s6[(2*y+1)*32 + 2*x] + s6[(2*y+1)*32 + 2*x + 1]);
    }
    __syncthreads();
    if (t < 32) {                               // r8: 4x8
        int y = t >> 3, x = t & 7;
        s8[t] = 0.25f * (s7[(2*y)*16 + 2*x] + s7[(2*y)*16 + 2*x + 1]
                       + s7[(2*y+1)*16 + 2*x] + s7[(2*y+1)*16 + 2*x + 1]);
    }
    __syncthreads();
    if (t < 8) {                                // r9: 2x4
        int y = t >> 2, x = t & 3;
        s9[t] = 0.25f * (s8[(2*y)*8 + 2*x] + s8[(2*y)*8 + 2*x + 1]
                       + s8[(2*y+1)*8 + 2*x] + s8[(2*y+1)*8 + 2*x + 1]);
    }
    __syncthreads();
    if (t < 2) {                                // r10: 1x2, and a10 = r10/DIAG
        s10[t] = 0.25f * (s9[2*t] + s9[2*t + 1] + s9[4 + 2*t] + s9[4 + 2*t + 1]);
        aA[t] = s10[t] * INV_DIAG;
    }
    __syncthreads();
    up_step(aB, aA, s9, 2, 4, t);    __syncthreads();   // a9
    up_step(aA, aB, s8, 4, 8, t);    __syncthreads();   // a8
    up_step(aB, aA, s7, 8, 16, t);   __syncthreads();   // a7
    up_step(aA, aB, s6, 16, 32, t);  __syncthreads();   // a6
    up_step(aB, aA, s5, 32, 64, t);  __syncthreads();   // a5
    up_step(a4g, aB, r4g, 64, 128, t);                  // a4 -> global
}

// ---- coarse-to-fine up-sweep at mid levels (1..3), grid version ----
__global__ void k_up(const float* __restrict__ a_in,
                     const float* __restrict__ r, float* __restrict__ a_out,
                     int H, int W) {
    int i = blockIdx.x * blockDim.x + threadIdx.x;
    if (i >= H * W) return;
    int y = i / W, x = i - y * W;
    int Wc = W >> 1;
    float m[3][3];
#pragma unroll
    for (int dy = 0; dy < 3; ++dy)
#pragma unroll
        for (int dx = 0; dx < 3; ++dx) {
            int yy = y + dy - 1, xx = x + dx - 1;
            m[dy][dx] = (yy >= 0 && yy < H && xx >= 0 && xx < W)
                            ? a_in[(yy >> 1) * Wc + (xx >> 1)] : 0.0f;
        }
    float conv = (m[0][0] + m[0][1] + m[0][2] + m[1][0] + m[1][2]
                  + m[2][0] + m[2][1] + m[2][2] - 8.0f * m[1][1]) * (1.0f / 3.0f);
    a_out[i] = m[1][1] - conv * INV_DIAG + r[i] * INV_DIAG;
}

// ---- fused: p' = p - P(a1);  p_new = p' - A(bc_p(p'))/DIAG + b/DIAG ----
__global__ __launch_bounds__(256) void k_pupdate(
        const float* __restrict__ p_src, const float* __restrict__ a1,
        const float* __restrict__ b, float* __restrict__ p_dst) {
    int x = blockIdx.x * blockDim.x + threadIdx.x;
    int y = blockIdx.y * blockDim.y + threadIdx.y;
    if (x >= GNX || y >= GNY) return;
    float m[3][3];
#pragma unroll
    for (int dy = 0; dy < 3; ++dy)
#pragma unroll
        for (int dx = 0; dx < 3; ++dx) {
            int yy = y + dy - 1, xx = x + dx - 1;
            float val;
            if (xx >= GNX) {
                val = 0.0f;  // bc_p right ghost (dominates corners)
            } else {
                if (xx < 0) xx = 0;
                yy = min(max(yy, 0), GNY - 1);
                val = p_src[yy * GNX + xx] - a1[(yy >> 1) * (GNX >> 1) + (xx >> 1)];
            }
            m[dy][dx] = val;
        }
    float conv = (m[0][0] + m[0][1] + m[0][2] + m[1][0] + m[1][2]
                  + m[2][0] + m[2][1] + m[2][2] - 8.0f * m[1][1]) * (1.0f / 3.0f);
    int idx = y * GNX + x;
    p_dst[idx] = m[1][1] - conv * INV_DIAG + b[idx] * INV_DIAG;
}

// ---- final projection (in-place on u2/v2) ----
__global__ __launch_bounds__(256) void k_project(
        const float* __restrict__ p, const float* __restrict__ sigma,
        float* __restrict__ u_io, float* __restrict__ v_io) {
    int x = blockIdx.x * blockDim.x + threadIdx.x;
    int y = blockIdx.y * blockDim.y + threadIdx.y;
    if (x >= GNX || y >= GNY) return;
    float pn[3][3];
#pragma unroll
    for (int dy = 0; dy < 3; ++dy)
#pragma unroll
        for (int dx = 0; dx < 3; ++dx)
            pn[dy][dx] = bc_p_at(p, y + dy - 1, x + dx - 1);
    int idx = y * GNX + x;
    float damp = 1.0f / (1.0f + DT * sigma[idx]);
    u_io[idx] = (u_io[idx] - conv_x3(pn) * DT) * damp;
    v_io[idx] = (v_io[idx] - conv_y3(pn) * DT) * damp;
}

extern "C" void kernel_launch(void* const* d_in, const int* in_sizes, int n_in,
                              void* d_out, int out_size, void* d_ws, size_t ws_size,
                              hipStream_t stream) {
    (void)in_sizes; (void)n_in; (void)out_size; (void)ws_size;
    const float* u_in  = (const float*)d_in[0];
    const float* v_in  = (const float*)d_in[1];
    const float* p_in  = (const float*)d_in[2];
    const float* sigma = (const float*)d_in[3];
    // d_in[4..8] are the fixed stencil weights — hardcoded above.

    float* out_u = (float*)d_out;
    float* out_v = out_u + GNPTS;
    float* out_p = out_u + 2 * (size_t)GNPTS;

    float* ws   = (float*)d_ws;
    float* bu   = ws;
    float* bv   = bu + (size_t)GNPTS;
    float* b    = bv + (size_t)GNPTS;
    float* p_ws = b  + (size_t)GNPTS;
    float* r1   = p_ws + (size_t)GNPTS;        // 512x1024
    float* r2   = r1 + 524288;                 // 256x512
    float* r3   = r2 + 131072;                 // 128x256
    float* r4   = r3 + 32768;                  // 64x128
    float* r5   = r4 + 8192;                   // 32x64
    float* a4   = r5 + 2048;                   // 64x128
    float* a_ping = a4 + 8192;                 // up to 512x1024
    float* a_pong = a_ping + 524288;

    dim3 blk2(64, 4), grd2(GNX / 64, GNY / 4);

    k_predict<<<grd2, blk2, 0, stream>>>(u_in, v_in, p_in, sigma, bu, bv);
    k_correct<<<grd2, blk2, 0, stream>>>(u_in, v_in, p_in, sigma, bu, bv, out_u, out_v);
    k_rhs<<<grd2, blk2, 0, stream>>>(out_u, out_v, b);

    const float* p_cur = p_in;          // pristine input p; read-only
    float* p_bufs[2] = { out_p, p_ws }; // it0->out_p, ..., it4->out_p
    for (int it = 0; it < 5; ++it) {
        k_resid_restrict<<<dim3(GNX / 32, GNY / 32), dim3(256), 0, stream>>>(
            p_cur, b, r1, r2, r3, r4, r5);
        k_coarse<<<dim3(1), dim3(256), 0, stream>>>(r5, r4, a4);
        // up levels 3,2,1
        k_up<<<dim3(32768 / 256), dim3(256), 0, stream>>>(a4, r3, a_ping, 128, 256);
        k_up<<<dim3(131072 / 256), dim3(256), 0, stream>>>(a_ping, r2, a_pong, 256, 512);
        k_up<<<dim3(524288 / 256), dim3(256), 0, stream>>>(a_pong, r1, a_ping, 512, 1024);
        float* p_next = p_bufs[it % 2];
        k_pupdate<<<grd2, blk2, 0, stream>>>(p_cur, a_ping, b, p_next);
        p_cur = p_next;
    }
    // p_cur == out_p here
    k_project<<<grd2, blk2, 0, stream>>>(p_cur, sigma, out_u, out_v);
}

// Round 3
// 239.016 us; speedup vs baseline: 1.9108x; 1.5617x over previous
//
#include <hip/hip_runtime.h>
#include <cstdint>

#define GNY 1024
#define GNX 2048
#define GNPTS (GNY * GNX)

namespace {
constexpr float DT = 0.1f;
constexpr float NUc = 0.01f;
constexpr float INV_DIAG = -0.375f;   // 1/DIAG, DIAG = -8/(3*dx^2) = -8/3
}

// ---- boundary-condition index maps (verified against JAX .at[].set order) ----
__device__ __forceinline__ float bc_u_at(const float* __restrict__ f, int y, int x) {
    if (y < 0 || y >= GNY || x < 0) return 1.0f;
    if (x >= GNX) x = GNX - 1;
    return f[y * GNX + x];
}
__device__ __forceinline__ float bc_v_at(const float* __restrict__ f, int y, int x) {
    if (y < 0 || y >= GNY || x < 0) return 0.0f;
    if (x >= GNX) x = GNX - 1;
    return f[y * GNX + x];
}
__device__ __forceinline__ float bc_p_at(const float* __restrict__ f, int y, int x) {
    if (x >= GNX) return 0.0f;          // right ghost = 0 (dominates corners)
    if (x < 0) x = 0;
    y = min(max(y, 0), GNY - 1);
    return f[y * GNX + x];
}

// ---- stencils (cross-correlation, m[dy][dx] = f(y+dy-1, x+dx-1)) ----
__device__ __forceinline__ float conv_x3(const float m[3][3]) {
    return ((m[0][2] - m[0][0]) + 4.0f * (m[1][2] - m[1][0]) + (m[2][2] - m[2][0])) * (1.0f / 12.0f);
}
__device__ __forceinline__ float conv_y3(const float m[3][3]) {
    return ((m[2][0] - m[0][0]) + 4.0f * (m[2][1] - m[0][1]) + (m[2][2] - m[0][2])) * (1.0f / 12.0f);
}
__device__ __forceinline__ float conv_d3(const float m[3][3]) {
    return (m[0][0] + m[0][1] + m[0][2] + m[1][0] + m[1][2] + m[2][0] + m[2][1] + m[2][2]
            - 8.0f * m[1][1]) * (1.0f / 3.0f);
}

// up-step value: a(y,x) = P(par)(y,x) - conv(bc0(P(par)))/DIAG + r/DIAG at level (H,W)
template <typename PG>
__device__ __forceinline__ float up_val(PG pget, float rval, int H, int W, int y, int x) {
    float m[3][3];
#pragma unroll
    for (int dy = 0; dy < 3; ++dy)
#pragma unroll
        for (int dx = 0; dx < 3; ++dx) {
            int yy = y + dy - 1, xx = x + dx - 1;
            m[dy][dx] = (yy >= 0 && yy < H && xx >= 0 && xx < W) ? pget(yy >> 1, xx >> 1) : 0.0f;
        }
    float conv = (m[0][0] + m[0][1] + m[0][2] + m[1][0] + m[1][2]
                  + m[2][0] + m[2][1] + m[2][2] - 8.0f * m[1][1]) * (1.0f / 3.0f);
    return m[1][1] - conv * INV_DIAG + rval * INV_DIAG;
}

// ---- momentum predictor: bu,bv (damped) ----
__global__ __launch_bounds__(256) void k_predict(
        const float* __restrict__ u, const float* __restrict__ v,
        const float* __restrict__ p, const float* __restrict__ sigma,
        float* __restrict__ bu, float* __restrict__ bv) {
    int x = blockIdx.x * blockDim.x + threadIdx.x;
    int y = blockIdx.y * blockDim.y + threadIdx.y;
    if (x >= GNX || y >= GNY) return;
    float un[3][3], vn[3][3], pn[3][3];
#pragma unroll
    for (int dy = 0; dy < 3; ++dy)
#pragma unroll
        for (int dx = 0; dx < 3; ++dx) {
            int yy = y + dy - 1, xx = x + dx - 1;
            un[dy][dx] = bc_u_at(u, yy, xx);
            vn[dy][dx] = bc_v_at(v, yy, xx);
            pn[dy][dx] = bc_p_at(p, yy, xx);
        }
    float gx = conv_x3(pn) * DT, gy = conv_y3(pn) * DT;
    float uc = un[1][1], vc = vn[1][1];
    float damp = 1.0f / (1.0f + DT * sigma[y * GNX + x]);
    float bu_ = uc + 0.5f * (NUc * conv_d3(un) * DT - uc * conv_x3(un) * DT - vc * conv_y3(un) * DT) - gx;
    float bv_ = vc + 0.5f * (NUc * conv_d3(vn) * DT - uc * conv_x3(vn) * DT - vc * conv_y3(vn) * DT) - gy;
    bu[y * GNX + x] = bu_ * damp;
    bv[y * GNX + x] = bv_ * damp;
}

// ---- momentum corrector (recomputes Grapx/Grapy from pristine p) ----
__global__ __launch_bounds__(256) void k_correct(
        const float* __restrict__ u, const float* __restrict__ v,
        const float* __restrict__ p, const float* __restrict__ sigma,
        const float* __restrict__ bu, const float* __restrict__ bv,
        float* __restrict__ u2, float* __restrict__ v2) {
    int x = blockIdx.x * blockDim.x + threadIdx.x;
    int y = blockIdx.y * blockDim.y + threadIdx.y;
    if (x >= GNX || y >= GNY) return;
    float bun[3][3], bvn[3][3], pn[3][3];
#pragma unroll
    for (int dy = 0; dy < 3; ++dy)
#pragma unroll
        for (int dx = 0; dx < 3; ++dx) {
            int yy = y + dy - 1, xx = x + dx - 1;
            bun[dy][dx] = bc_u_at(bu, yy, xx);
            bvn[dy][dx] = bc_v_at(bv, yy, xx);
            pn[dy][dx] = bc_p_at(p, yy, xx);
        }
    float gx = conv_x3(pn) * DT, gy = conv_y3(pn) * DT;
    float buc = bun[1][1], bvc = bvn[1][1];
    int idx = y * GNX + x;
    float damp = 1.0f / (1.0f + DT * sigma[idx]);
    float un_ = u[idx] + NUc * conv_d3(bun) * DT - buc * conv_x3(bun) * DT - bvc * conv_y3(bun) * DT - gx;
    float vn_ = v[idx] + NUc * conv_d3(bvn) * DT - buc * conv_x3(bvn) * DT - bvc * conv_y3(bvn) * DT - gy;
    u2[idx] = un_ * damp;
    v2[idx] = vn_ * damp;
}

// ---- MG rhs: b = -(d/dx u + d/dy v)/DT ----
__global__ __launch_bounds__(256) void k_rhs(
        const float* __restrict__ u2, const float* __restrict__ v2, float* __restrict__ b) {
    int x = blockIdx.x * blockDim.x + threadIdx.x;
    int y = blockIdx.y * blockDim.y + threadIdx.y;
    if (x >= GNX || y >= GNY) return;
    float un[3][3], vn[3][3];
#pragma unroll
    for (int dy = 0; dy < 3; ++dy)
#pragma unroll
        for (int dx = 0; dx < 3; ++dx) {
            int yy = y + dy - 1, xx = x + dx - 1;
            un[dy][dx] = bc_u_at(u2, yy, xx);
            vn[dy][dx] = bc_v_at(v2, yy, xx);
        }
    b[y * GNX + x] = -(conv_x3(un) + conv_y3(vn)) * (1.0f / DT);
}

// ---- initial residual + restriction to levels 1..5 (32x32 tile per WG) ----
__global__ __launch_bounds__(256) void k_resid_restrict(
        const float* __restrict__ p, const float* __restrict__ b,
        float* __restrict__ r1, float* __restrict__ r2, float* __restrict__ r3,
        float* __restrict__ r4, float* __restrict__ r5) {
    __shared__ float s0[32][33];
    __shared__ float s1[16][17];
    __shared__ float s2[8][9];
    __shared__ float s3[4][5];
    __shared__ float s4[2][3];
    int t = threadIdx.x;
    int tx = t & 31, tg = t >> 5;
    int x0 = blockIdx.x * 32, y0 = blockIdx.y * 32;
    int x = x0 + tx;
#pragma unroll
    for (int ry = 0; ry < 4; ++ry) {
        int yr = tg * 4 + ry;
        int y = y0 + yr;
        float pn[3][3];
#pragma unroll
        for (int dy = 0; dy < 3; ++dy)
#pragma unroll
            for (int dx = 0; dx < 3; ++dx)
                pn[dy][dx] = bc_p_at(p, y + dy - 1, x + dx - 1);
        s0[yr][tx] = conv_d3(pn) - b[y * GNX + x];
    }
    __syncthreads();
    {   int qy = t >> 4, qx = t & 15;
        float v = 0.25f * (s0[2*qy][2*qx] + s0[2*qy][2*qx+1] + s0[2*qy+1][2*qx] + s0[2*qy+1][2*qx+1]);
        s1[qy][qx] = v;
        r1[(blockIdx.y * 16 + qy) * 1024 + blockIdx.x * 16 + qx] = v; }
    __syncthreads();
    if (t < 64) { int qy = t >> 3, qx = t & 7;
        float v = 0.25f * (s1[2*qy][2*qx] + s1[2*qy][2*qx+1] + s1[2*qy+1][2*qx] + s1[2*qy+1][2*qx+1]);
        s2[qy][qx] = v;
        r2[(blockIdx.y * 8 + qy) * 512 + blockIdx.x * 8 + qx] = v; }
    __syncthreads();
    if (t < 16) { int qy = t >> 2, qx = t & 3;
        float v = 0.25f * (s2[2*qy][2*qx] + s2[2*qy][2*qx+1] + s2[2*qy+1][2*qx] + s2[2*qy+1][2*qx+1]);
        s3[qy][qx] = v;
        r3[(blockIdx.y * 4 + qy) * 256 + blockIdx.x * 4 + qx] = v; }
    __syncthreads();
    if (t < 4) { int qy = t >> 1, qx = t & 1;
        float v = 0.25f * (s3[2*qy][2*qx] + s3[2*qy][2*qx+1] + s3[2*qy+1][2*qx] + s3[2*qy+1][2*qx+1]);
        s4[qy][qx] = v;
        r4[(blockIdx.y * 2 + qy) * 128 + blockIdx.x * 2 + qx] = v; }
    __syncthreads();
    if (t == 0)
        r5[blockIdx.y * 64 + blockIdx.x] = 0.25f * (s4[0][0] + s4[0][1] + s4[1][0] + s4[1][1]);
}

// ---- ONE fused MG iteration: per-WG redundant coarse solve + windowed up-sweep
//      + p-update + (next residual pyramid | projection) ----
__global__ __launch_bounds__(256) void k_mg(
        const float* __restrict__ p_src, const float* __restrict__ b,
        const float* __restrict__ r1, const float* __restrict__ r2,
        const float* __restrict__ r3, const float* __restrict__ r4,
        const float* __restrict__ r5,
        float* __restrict__ p_dst,
        float* __restrict__ o1, float* __restrict__ o2, float* __restrict__ o3,
        float* __restrict__ o4, float* __restrict__ o5,
        const float* __restrict__ sigma, float* __restrict__ u_io,
        float* __restrict__ v_io, int last) {
    // phase-overlaid scratch: coarse pyramid (phase 1-2) then p'/p_next/restrict (phase 3)
    __shared__ float scr[3948];
    __shared__ float w6v[9], w5v[9], w4v[16], w3v[36], w2v[100], w1v[324];
    float* s5  = scr;            // 32x64 = 2048
    float* s6  = scr + 2048;     // 16x32 = 512
    float* s7  = scr + 2560;     // 8x16  = 128
    float* s8  = scr + 2688;     // 4x8   = 32
    float* s9  = scr + 2720;     // 2x4   = 8
    float* s10 = scr + 2728;     // 1x2   = 2
    float* a9  = scr + 2730;     // 8
    float* a8  = scr + 2738;     // 32
    float* a7  = scr + 2770;     // 128  (phase1 total 2898)
    // phase 3 overlay (after w1v is final):
    float* sPp = scr;            // 36x36, stride 37 = 1332
    float* sPn = scr + 1332;     // 34x34, stride 35 = 1190
    float* s0  = scr + 2522;     // 32x33 = 1056
    float* s1  = scr + 3578;     // 16x17 = 272
    float* s2  = scr + 3850;     // 8x9   = 72
    float* s3  = scr + 3922;     // 4x5   = 20
    float* s4  = scr + 3942;     // 2x3   = 6   (total 3948)

    int t = threadIdx.x;
    int bx = blockIdx.x, by = blockIdx.y;
    int y0 = by * 32, x0 = bx * 32;

    // ---- phase 1: full restriction r5 -> r10, tiny full up levels a10->a7 ----
    for (int i = t; i < 2048; i += 256) s5[i] = r5[i];
    __syncthreads();
    for (int i = t; i < 512; i += 256) {
        int y = i >> 5, x = i & 31;
        s6[i] = 0.25f * (s5[(2*y)*64 + 2*x] + s5[(2*y)*64 + 2*x + 1]
                       + s5[(2*y+1)*64 + 2*x] + s5[(2*y+1)*64 + 2*x + 1]);
    }
    __syncthreads();
    if (t < 128) { int y = t >> 4, x = t & 15;
        s7[t] = 0.25f * (s6[(2*y)*32 + 2*x] + s6[(2*y)*32 + 2*x + 1]
                       + s6[(2*y+1)*32 + 2*x] + s6[(2*y+1)*32 + 2*x + 1]); }
    __syncthreads();
    if (t < 32) { int y = t >> 3, x = t & 7;
        s8[t] = 0.25f * (s7[(2*y)*16 + 2*x] + s7[(2*y)*16 + 2*x + 1]
                       + s7[(2*y+1)*16 + 2*x] + s7[(2*y+1)*16 + 2*x + 1]); }
    __syncthreads();
    if (t < 8) { int y = t >> 2, x = t & 3;
        s9[t] = 0.25f * (s8[(2*y)*8 + 2*x] + s8[(2*y)*8 + 2*x + 1]
                       + s8[(2*y+1)*8 + 2*x] + s8[(2*y+1)*8 + 2*x + 1]); }
    __syncthreads();
    if (t < 2)
        s10[t] = 0.25f * (s9[2*t] + s9[2*t + 1] + s9[4 + 2*t] + s9[4 + 2*t + 1]);
    __syncthreads();
    if (t < 8) { int y = t >> 2, x = t & 3;  // a9 full 2x4
        a9[t] = up_val([&](int py, int px) { return s10[py*2 + px] * INV_DIAG; },
                       s9[t], 2, 4, y, x); }
    __syncthreads();
    if (t < 32) { int y = t >> 3, x = t & 7; // a8 full 4x8
        a8[t] = up_val([&](int py, int px) { return a9[py*4 + px]; },
                       s8[t], 4, 8, y, x); }
    __syncthreads();
    if (t < 128) { int y = t >> 4, x = t & 15; // a7 full 8x16
        a7[t] = up_val([&](int py, int px) { return a8[py*8 + px]; },
                       s7[t], 8, 16, y, x); }
    __syncthreads();

    // ---- phase 2: windowed up-sweep a6..a1 (windows per the parent recurrence) ----
    int w6ylo = (by - 2) >> 1, w6xlo = (bx - 2) >> 1;
    int w5ylo = by - 1,        w5xlo = bx - 1;
    int w4ylo = 2*by - 1,      w4xlo = 2*bx - 1;
    int w3ylo = 4*by - 1,      w3xlo = 4*bx - 1;
    int w2ylo = 8*by - 1,      w2xlo = 8*bx - 1;
    int w1ylo = 16*by - 1,     w1xlo = 16*bx - 1;

    if (t < 9) { int gy = w6ylo + t/3, gx = w6xlo + t%3;   // level 6: 16x32
        w6v[t] = (gy >= 0 && gy < 16 && gx >= 0 && gx < 32)
            ? up_val([&](int py, int px) { return a7[py*16 + px]; },
                     s6[gy*32 + gx], 16, 32, gy, gx) : 0.0f; }
    __syncthreads();
    if (t < 9) { int gy = w5ylo + t/3, gx = w5xlo + t%3;   // level 5: 32x64
        w5v[t] = (gy >= 0 && gy < 32 && gx >= 0 && gx < 64)
            ? up_val([&](int py, int px) { return w6v[(py - w6ylo)*3 + (px - w6xlo)]; },
                     s5[gy*64 + gx], 32, 64, gy, gx) : 0.0f; }
    __syncthreads();
    if (t < 16) { int gy = w4ylo + t/4, gx = w4xlo + t%4;  // level 4: 64x128
        w4v[t] = (gy >= 0 && gy < 64 && gx >= 0 && gx < 128)
            ? up_val([&](int py, int px) { return w5v[(py - w5ylo)*3 + (px - w5xlo)]; },
                     r4[gy*128 + gx], 64, 128, gy, gx) : 0.0f; }
    __syncthreads();
    if (t < 36) { int gy = w3ylo + t/6, gx = w3xlo + t%6;  // level 3: 128x256
        w3v[t] = (gy >= 0 && gy < 128 && gx >= 0 && gx < 256)
            ? up_val([&](int py, int px) { return w4v[(py - w4ylo)*4 + (px - w4xlo)]; },
                     r3[gy*256 + gx], 128, 256, gy, gx) : 0.0f; }
    __syncthreads();
    if (t < 100) { int gy = w2ylo + t/10, gx = w2xlo + t%10; // level 2: 256x512
        w2v[t] = (gy >= 0 && gy < 256 && gx >= 0 && gx < 512)
            ? up_val([&](int py, int px) { return w3v[(py - w3ylo)*6 + (px - w3xlo)]; },
                     r2[gy*512 + gx], 256, 512, gy, gx) : 0.0f; }
    __syncthreads();
    for (int i = t; i < 324; i += 256) { int gy = w1ylo + i/18, gx = w1xlo + i%18; // level 1
        w1v[i] = (gy >= 0 && gy < 512 && gx >= 0 && gx < 1024)
            ? up_val([&](int py, int px) { return w2v[(py - w2ylo)*10 + (px - w2xlo)]; },
                     r1[gy*1024 + gx], 512, 1024, gy, gx) : 0.0f; }
    __syncthreads();

    // ---- phase 3: p' = p - P(a1) on 36x36 window ----
    for (int i = t; i < 1296; i += 256) {
        int wy = i / 36, wx = i % 36;
        int gy = y0 - 2 + wy, gx = x0 - 2 + wx;
        float v = 0.0f;
        if (gy >= 0 && gy < GNY && gx >= 0 && gx < GNX)
            v = p_src[gy*GNX + gx] - w1v[((gy >> 1) - w1ylo)*18 + ((gx >> 1) - w1xlo)];
        sPp[wy*37 + wx] = v;
    }
    __syncthreads();
    // p_next on 34x34 window: p' - A(bc_p(p'))/DIAG + b/DIAG
    for (int i = t; i < 1156; i += 256) {
        int wy = i / 34, wx = i % 34;
        int gy = y0 - 1 + wy, gx = x0 - 1 + wx;
        float v = 0.0f;
        if (gy >= 0 && gy < GNY && gx >= 0 && gx < GNX) {
            float m[3][3];
#pragma unroll
            for (int dy = 0; dy < 3; ++dy)
#pragma unroll
                for (int dx = 0; dx < 3; ++dx) {
                    int yy = gy + dy - 1, xx = gx + dx - 1;
                    float tv;
                    if (xx >= GNX) tv = 0.0f;
                    else {
                        int cx = xx < 0 ? 0 : xx;
                        int cy = min(max(yy, 0), GNY - 1);
                        tv = sPp[(cy - (y0 - 2))*37 + (cx - (x0 - 2))];
                    }
                    m[dy][dx] = tv;
                }
            float conv = (m[0][0] + m[0][1] + m[0][2] + m[1][0] + m[1][2]
                          + m[2][0] + m[2][1] + m[2][2] - 8.0f*m[1][1]) * (1.0f / 3.0f);
            v = m[1][1] - conv * INV_DIAG + b[gy*GNX + gx] * INV_DIAG;
        }
        sPn[wy*35 + wx] = v;
    }
    __syncthreads();
    // write own p tile
    for (int i = t; i < 1024; i += 256) {
        int ty = i >> 5, tx = i & 31;
        p_dst[(y0 + ty)*GNX + x0 + tx] = sPn[(ty + 1)*35 + (tx + 1)];
    }

    if (!last) {
        // ---- next-iteration residual r0 on tile + restriction to o1..o5 ----
        for (int i = t; i < 1024; i += 256) {
            int ty = i >> 5, tx = i & 31;
            int gy = y0 + ty, gx = x0 + tx;
            float m[3][3];
#pragma unroll
            for (int dy = 0; dy < 3; ++dy)
#pragma unroll
                for (int dx = 0; dx < 3; ++dx) {
                    int yy = gy + dy - 1, xx = gx + dx - 1;
                    float tv;
                    if (xx >= GNX) tv = 0.0f;
                    else {
                        int cx = xx < 0 ? 0 : xx;
                        int cy = min(max(yy, 0), GNY - 1);
                        tv = sPn[(cy - (y0 - 1))*35 + (cx - (x0 - 1))];
                    }
                    m[dy][dx] = tv;
                }
            s0[ty*33 + tx] = conv_d3(m) - b[gy*GNX + gx];
        }
        __syncthreads();
        { int qy = t >> 4, qx = t & 15;
          float v = 0.25f * (s0[(2*qy)*33 + 2*qx] + s0[(2*qy)*33 + 2*qx + 1]
                           + s0[(2*qy+1)*33 + 2*qx] + s0[(2*qy+1)*33 + 2*qx + 1]);
          s1[qy*17 + qx] = v;
          o1[(by*16 + qy)*1024 + bx*16 + qx] = v; }
        __syncthreads();
        if (t < 64) { int qy = t >> 3, qx = t & 7;
          float v = 0.25f * (s1[(2*qy)*17 + 2*qx] + s1[(2*qy)*17 + 2*qx + 1]
                           + s1[(2*qy+1)*17 + 2*qx] + s1[(2*qy+1)*17 + 2*qx + 1]);
          s2[qy*9 + qx] = v;
          o2[(by*8 + qy)*512 + bx*8 + qx] = v; }
        __syncthreads();
        if (t < 16) { int qy = t >> 2, qx = t & 3;
          float v = 0.25f * (s2[(2*qy)*9 + 2*qx] + s2[(2*qy)*9 + 2*qx + 1]
                           + s2[(2*qy+1)*9 + 2*qx] + s2[(2*qy+1)*9 + 2*qx + 1]);
          s3[qy*5 + qx] = v;
          o3[(by*4 + qy)*256 + bx*4 + qx] = v; }
        __syncthreads();
        if (t < 4) { int qy = t >> 1, qx = t & 1;
          float v = 0.25f * (s3[(2*qy)*5 + 2*qx] + s3[(2*qy)*5 + 2*qx + 1]
                           + s3[(2*qy+1)*5 + 2*qx] + s3[(2*qy+1)*5 + 2*qx + 1]);
          s4[qy*3 + qx] = v;
          o4[(by*2 + qy)*128 + bx*2 + qx] = v; }
        __syncthreads();
        if (t == 0)
            o5[by*64 + bx] = 0.25f * (s4[0] + s4[1] + s4[3] + s4[4]);
    } else {
        // ---- fused projection: u -= dp/dx*DT etc., damped ----
        for (int i = t; i < 1024; i += 256) {
            int ty = i >> 5, tx = i & 31;
            int gy = y0 + ty, gx = x0 + tx;
            float m[3][3];
#pragma unroll
            for (int dy = 0; dy < 3; ++dy)
#pragma unroll
                for (int dx = 0; dx < 3; ++dx) {
                    int yy = gy + dy - 1, xx = gx + dx - 1;
                    float tv;
                    if (xx >= GNX) tv = 0.0f;
                    else {
                        int cx = xx < 0 ? 0 : xx;
                        int cy = min(max(yy, 0), GNY - 1);
                        tv = sPn[(cy - (y0 - 1))*35 + (cx - (x0 - 1))];
                    }
                    m[dy][dx] = tv;
                }
            int idx = gy*GNX + gx;
            float damp = 1.0f / (1.0f + DT * sigma[idx]);
            u_io[idx] = (u_io[idx] - conv_x3(m) * DT) * damp;
            v_io[idx] = (v_io[idx] - conv_y3(m) * DT) * damp;
        }
    }
}

extern "C" void kernel_launch(void* const* d_in, const int* in_sizes, int n_in,
                              void* d_out, int out_size, void* d_ws, size_t ws_size,
                              hipStream_t stream) {
    (void)in_sizes; (void)n_in; (void)out_size; (void)ws_size;
    const float* u_in  = (const float*)d_in[0];
    const float* v_in  = (const float*)d_in[1];
    const float* p_in  = (const float*)d_in[2];
    const float* sigma = (const float*)d_in[3];

    float* out_u = (float*)d_out;
    float* out_v = out_u + GNPTS;
    float* out_p = out_u + 2 * (size_t)GNPTS;

    float* ws   = (float*)d_ws;
    float* bu   = ws;
    float* bv   = bu + (size_t)GNPTS;
    float* b    = bv + (size_t)GNPTS;
    float* p_ws = b  + (size_t)GNPTS;
    float* base = p_ws + (size_t)GNPTS;
    // two residual pyramids (levels 1..5)
    float* A_[5], * B_[5];
    size_t lsz[5] = {524288, 131072, 32768, 8192, 2048};
    float* cur = base;
    for (int l = 0; l < 5; ++l) { A_[l] = cur; cur += lsz[l]; }
    for (int l = 0; l < 5; ++l) { B_[l] = cur; cur += lsz[l]; }

    dim3 blk2(64, 4), grd2(GNX / 64, GNY / 4);
    dim3 grdT(GNX / 32, GNY / 32), blkT(256);

    k_predict<<<grd2, blk2, 0, stream>>>(u_in, v_in, p_in, sigma, bu, bv);
    k_correct<<<grd2, blk2, 0, stream>>>(u_in, v_in, p_in, sigma, bu, bv, out_u, out_v);
    k_rhs<<<grd2, blk2, 0, stream>>>(out_u, out_v, b);

    k_resid_restrict<<<grdT, blkT, 0, stream>>>(p_in, b, A_[0], A_[1], A_[2], A_[3], A_[4]);

    const float* p_cur = p_in;
    float* p_bufs[2] = { out_p, p_ws };   // it0->out_p, it1->p_ws, ..., it4->out_p
    for (int it = 0; it < 5; ++it) {
        float** rp = (it % 2 == 0) ? A_ : B_;   // read pyramid
        float** wp = (it % 2 == 0) ? B_ : A_;   // write pyramid
        float* p_next = p_bufs[it % 2];
        int last = (it == 4) ? 1 : 0;
        k_mg<<<grdT, blkT, 0, stream>>>(p_cur, b,
                                        rp[0], rp[1], rp[2], rp[3], rp[4],
                                        p_next,
                                        wp[0], wp[1], wp[2], wp[3], wp[4],
                                        sigma, out_u, out_v, last);
        p_cur = p_next;
    }
}